// Round 8
// baseline (383.368 us; speedup 1.0000x reference)
//
#include <hip/hip_runtime.h>
#include <hip/hip_bf16.h>

#define NH 12
#define HD 64
#define DM 768
#define SEQ 1024
#define BATCH 8

typedef __attribute__((ext_vector_type(8))) short bf16x8;
typedef __attribute__((ext_vector_type(4))) short s16x4;
typedef __attribute__((ext_vector_type(4))) float f32x4;

__device__ __forceinline__ short f2b(float x) {
    unsigned u = __float_as_uint(x);
    u += 0x7fffu + ((u >> 16) & 1u);    // RNE to bf16 (finite values)
    return (short)(u >> 16);
}

#define MFMA(A, B, C) __builtin_amdgcn_mfma_f32_16x16x32_bf16(A, B, C, 0, 0, 0)

// ---------------------------------------------------------------------------
// f32 -> bf16 conversion (vectorized x4)
// ---------------------------------------------------------------------------
__global__ __launch_bounds__(256) void cvt_f32_bf16(
    const float* __restrict__ in, short* __restrict__ out, int n4)
{
    int i = blockIdx.x * 256 + threadIdx.x;
    if (i < n4) {
        f32x4 v = *(const f32x4*)(in + 4 * (size_t)i);
        s16x4 r;
        r[0] = f2b(v[0]); r[1] = f2b(v[1]); r[2] = f2b(v[2]); r[3] = f2b(v[3]);
        *(s16x4*)(out + 4 * (size_t)i) = r;
    }
}

// ---------------------------------------------------------------------------
// QKV projection, bf16 MFMA. 128x64 output tile, 8 waves (512 thr), BK=64.
// Wave w owns rows [w*16, w*16+16); W-tile staged once, shared by all waves.
// z==2 (V) scatters output transposed into vt[b][h][d][j].
// ---------------------------------------------------------------------------
__global__ __launch_bounds__(512, 4) void qkv_mfma(
    const short* __restrict__ xb,
    const short* __restrict__ wqb, const float* __restrict__ bq,
    const short* __restrict__ wkb, const float* __restrict__ bk,
    const short* __restrict__ wvb, const float* __restrict__ bv,
    short* __restrict__ qb, short* __restrict__ kb, short* __restrict__ vt)
{
    __shared__ short Xl[128][72];   // 18 KB
    __shared__ short Wl[64][72];    //  9 KB

    const int orig = blockIdx.x;                 // 2304 blocks, %8==0
    const int sw   = (orig & 7) * 288 + (orig >> 3);
    const int t    = sw % 36;
    const int by   = t % 12;
    const int z    = t / 12;
    const int bx   = sw / 36;                    // 0..63

    const short* wmat = (z == 0) ? wqb : (z == 1) ? wkb : wvb;
    const float* bias = (z == 0) ? bq : (z == 1) ? bk : bv;

    const int i0   = bx * 128;
    const int col0 = by * 64;
    const int tid  = threadIdx.x;
    const int lane = tid & 63;
    const int w    = tid >> 6;
    const int lg   = lane >> 4;
    const int lc   = lane & 15;

    const int sr = tid >> 3, scx = (tid & 7) * 8;

    f32x4 acc[4] = {};
    for (int k0 = 0; k0 < DM; k0 += 64) {
        __syncthreads();    // protect Xl/Wl reuse
        *(bf16x8*)&Xl[sr][scx] =
            *(const bf16x8*)&xb[(size_t)(i0 + sr) * DM + k0 + scx];
        *(bf16x8*)&Xl[sr + 64][scx] =
            *(const bf16x8*)&xb[(size_t)(i0 + 64 + sr) * DM + k0 + scx];
        *(bf16x8*)&Wl[sr][scx] =
            *(const bf16x8*)&wmat[(size_t)(col0 + sr) * DM + k0 + scx];
        __syncthreads();
        #pragma unroll
        for (int kh = 0; kh < 2; ++kh) {
            const bf16x8 a = *(const bf16x8*)&Xl[w * 16 + lc][kh * 32 + lg * 8];
            #pragma unroll
            for (int n = 0; n < 4; ++n) {
                const bf16x8 bfr = *(const bf16x8*)&Wl[n * 16 + lc][kh * 32 + lg * 8];
                acc[n] = MFMA(a, bfr, acc[n]);
            }
        }
    }

    if (z < 2) {
        short* outp = (z == 0) ? qb : kb;
        #pragma unroll
        for (int n = 0; n < 4; ++n) {
            const int c = col0 + n * 16 + lc;
            const float bi = bias[c];
            #pragma unroll
            for (int rr = 0; rr < 4; ++rr) {
                const int r = i0 + w * 16 + lg * 4 + rr;
                outp[(size_t)r * DM + c] = f2b(acc[n][rr] + bi);
            }
        }
    } else {
        #pragma unroll
        for (int n = 0; n < 4; ++n) {
            const int c = col0 + n * 16 + lc;     // o = h*64 + d
            const int h = c >> 6, d = c & 63;
            const float bi = bias[c];
            #pragma unroll
            for (int rr = 0; rr < 4; ++rr) {
                const int r  = i0 + w * 16 + lg * 4 + rr;   // b*1024 + j
                const int bb = r >> 10, j = r & 1023;
                vt[(((size_t)bb * NH + h) * HD + d) * SEQ + j] = f2b(acc[n][rr] + bi);
            }
        }
    }
}

// ---------------------------------------------------------------------------
// Flash MFMA attention, within-wave softmax.
// Block = 128 Q-rows x (h,b), 8 waves; wave w owns rows [w*16,w*16+16) for
// ALL j. j-chunks of 64. Per chunk/wave: T bias tiles (5) in REGISTERS via
// MFMA(Q, demb-window); QK (4 tiles); bias gather = 2 shfl + select
// (tile idx compile-time); online softmax within-wave (shfl_xor reduce);
// P -> per-wave LDS (no barrier); PV from global V^T. 2 barriers/chunk
// around K/D staging, with global->reg preload overlap (T14 split).
// ---------------------------------------------------------------------------
__global__ __launch_bounds__(512, 4) void attn_flash(
    const short* __restrict__ qb, const short* __restrict__ kb,
    const short* __restrict__ vt, const short* __restrict__ deb,
    float* __restrict__ out)
{
    const int orig = blockIdx.x;                 // 768 blocks, %8==0
    const int sw   = (orig & 7) * 96 + (orig >> 3);
    const int bx   = sw & 7;
    const int rest = sw >> 3;
    const int h    = rest % NH;
    const int b    = rest / NH;

    const int i0   = bx * 128;
    const int tid  = threadIdx.x;
    const int lane = tid & 63;
    const int w    = tid >> 6;        // 0..7
    const int wR   = w * 16;
    const int lg   = lane >> 4;
    const int lc   = lane & 15;

    __shared__ short Kl[64][72];          //  9 KB
    __shared__ short Dl[192][72];         // 27 KB (demb window for 128 rows)
    __shared__ short Pl[8][16][136];      // 34 KB (per-wave P buffers)

    // Q A-fragments (held whole kernel)
    const short* qrow = qb + ((size_t)(b * SEQ + i0 + wR + lc)) * DM + h * HD;
    const bf16x8 A0 = *(const bf16x8*)(qrow + lg * 8);
    const bf16x8 A1 = *(const bf16x8*)(qrow + 32 + lg * 8);

    const short* kbase = kb + (size_t)(b * SEQ) * DM + h * HD;
    const short* vbase = vt + ((size_t)(b * NH + h) * HD) * SEQ;

    // staging: global->reg (issued early), reg->LDS (after bar1)
    const int sr = tid >> 3, scx = (tid & 7) * 8;
    bf16x8 kreg, dreg0, dreg1, dreg2;

    auto stage_load = [&](int jc) {
        kreg = *(const bf16x8*)&kbase[(size_t)(jc + sr) * DM + scx];
        const int wb = i0 - jc + 960;               // demb row base, >= 0
        const int r2 = min(wb + sr + 128, 2046);    // clamp (row 191 unused)
        dreg0 = *(const bf16x8*)&deb[(size_t)(wb + sr) * HD + scx];
        dreg1 = *(const bf16x8*)&deb[(size_t)(wb + sr + 64) * HD + scx];
        dreg2 = *(const bf16x8*)&deb[(size_t)r2 * HD + scx];
    };
    auto stage_store = [&]() {
        *(bf16x8*)&Kl[sr][scx]       = kreg;
        *(bf16x8*)&Dl[sr][scx]       = dreg0;
        *(bf16x8*)&Dl[sr + 64][scx]  = dreg1;
        *(bf16x8*)&Dl[sr + 128][scx] = dreg2;
    };

    float m[4], l[4];
    f32x4 O0 = {0.f,0.f,0.f,0.f}, O1 = {0.f,0.f,0.f,0.f};
    f32x4 O2 = {0.f,0.f,0.f,0.f}, O3 = {0.f,0.f,0.f,0.f};
    #pragma unroll
    for (int rr = 0; rr < 4; ++rr) { m[rr] = -1e30f; l[rr] = 0.f; }

    stage_load(0);
    stage_store();
    __syncthreads();

    for (int c = 0; c < 16; ++c) {
        const int jc = c * 64;
        if (c < 15) stage_load(jc + 64);   // preload next chunk (overlaps MFMAs)

        // ---- T bias tiles (registers): T[t][q=lg*4+rr][dcol=lc] ----
        f32x4 T0, T1, T2, T3, T4;
        {
            f32x4 a;
            a = f32x4{0.f,0.f,0.f,0.f};
            a = MFMA(A0, *(const bf16x8*)&Dl[wR + 0*16 + lc][lg*8], a);
            T0 = MFMA(A1, *(const bf16x8*)&Dl[wR + 0*16 + lc][32 + lg*8], a);
            a = f32x4{0.f,0.f,0.f,0.f};
            a = MFMA(A0, *(const bf16x8*)&Dl[wR + 1*16 + lc][lg*8], a);
            T1 = MFMA(A1, *(const bf16x8*)&Dl[wR + 1*16 + lc][32 + lg*8], a);
            a = f32x4{0.f,0.f,0.f,0.f};
            a = MFMA(A0, *(const bf16x8*)&Dl[wR + 2*16 + lc][lg*8], a);
            T2 = MFMA(A1, *(const bf16x8*)&Dl[wR + 2*16 + lc][32 + lg*8], a);
            a = f32x4{0.f,0.f,0.f,0.f};
            a = MFMA(A0, *(const bf16x8*)&Dl[wR + 3*16 + lc][lg*8], a);
            T3 = MFMA(A1, *(const bf16x8*)&Dl[wR + 3*16 + lc][32 + lg*8], a);
            a = f32x4{0.f,0.f,0.f,0.f};
            a = MFMA(A0, *(const bf16x8*)&Dl[wR + 4*16 + lc][lg*8], a);
            T4 = MFMA(A1, *(const bf16x8*)&Dl[wR + 4*16 + lc][32 + lg*8], a);
        }

        // ---- QK tiles ----
        f32x4 sv[4];
        #pragma unroll
        for (int jt = 0; jt < 4; ++jt) {
            f32x4 s = {0.f,0.f,0.f,0.f};
            s = MFMA(A0, *(const bf16x8*)&Kl[jt*16 + lc][lg*8], s);
            s = MFMA(A1, *(const bf16x8*)&Kl[jt*16 + lc][32 + lg*8], s);
            sv[jt] = s;
        }
        __syncthreads();   // bar1: all Kl/Dl reads of chunk c complete

        // ---- bias gather (T in regs, 2 shfl + select) + chunk max ----
        float mw[4] = {-1e30f, -1e30f, -1e30f, -1e30f};
        #pragma unroll
        for (int jt = 0; jt < 4; ++jt) {
            #pragma unroll
            for (int rr = 0; rr < 4; ++rr) {
                const int loff = 63 + lg * 4 + rr - jt * 16 - lc;   // 0..78
                const int src  = (lane & 48) | (loff & 15);
                float c0, c1;
                if (jt == 0)      { c0 = __shfl(T3[rr], src, 64); c1 = __shfl(T4[rr], src, 64); }
                else if (jt == 1) { c0 = __shfl(T2[rr], src, 64); c1 = __shfl(T3[rr], src, 64); }
                else if (jt == 2) { c0 = __shfl(T1[rr], src, 64); c1 = __shfl(T2[rr], src, 64); }
                else              { c0 = __shfl(T0[rr], src, 64); c1 = __shfl(T1[rr], src, 64); }
                const int tlo = 3 - jt;
                float bias = ((loff >> 4) == tlo) ? c0 : c1;
                sv[jt][rr] += bias;
                mw[rr] = fmaxf(mw[rr], sv[jt][rr]);
            }
        }

        // ---- within-wave online softmax ----
        float scale[4];
        #pragma unroll
        for (int rr = 0; rr < 4; ++rr) {
            float v = mw[rr];
            v = fmaxf(v, __shfl_xor(v, 1, 64));
            v = fmaxf(v, __shfl_xor(v, 2, 64));
            v = fmaxf(v, __shfl_xor(v, 4, 64));
            v = fmaxf(v, __shfl_xor(v, 8, 64));
            const float mn = fmaxf(m[rr], v);
            scale[rr] = __expf((m[rr] - mn) * 0.125f);
            m[rr] = mn;
            float s = 0.f;
            #pragma unroll
            for (int jt = 0; jt < 4; ++jt) {
                const float p = __expf((sv[jt][rr] - mn) * 0.125f);
                Pl[w][lg * 4 + rr][jt * 16 + lc] = f2b(p);
                s += p;
            }
            s += __shfl_xor(s, 1, 64);
            s += __shfl_xor(s, 2, 64);
            s += __shfl_xor(s, 4, 64);
            s += __shfl_xor(s, 8, 64);
            l[rr] = l[rr] * scale[rr] + s;
        }

        if (c < 15) stage_store();   // ds_write next chunk (Kl/Dl free since bar1)

        // ---- O rescale + PV ----
        #pragma unroll
        for (int rr = 0; rr < 4; ++rr) {
            O0[rr] *= scale[rr]; O1[rr] *= scale[rr];
            O2[rr] *= scale[rr]; O3[rr] *= scale[rr];
        }
        #pragma unroll
        for (int ks = 0; ks < 2; ++ks) {
            const bf16x8 Af = *(const bf16x8*)&Pl[w][lc][ks * 32 + lg * 8];
            const size_t vo = jc + ks * 32 + lg * 8;
            O0 = MFMA(Af, *(const bf16x8*)&vbase[(size_t)( 0 + lc) * SEQ + vo], O0);
            O1 = MFMA(Af, *(const bf16x8*)&vbase[(size_t)(16 + lc) * SEQ + vo], O1);
            O2 = MFMA(Af, *(const bf16x8*)&vbase[(size_t)(32 + lc) * SEQ + vo], O2);
            O3 = MFMA(Af, *(const bf16x8*)&vbase[(size_t)(48 + lc) * SEQ + vo], O3);
        }
        __syncthreads();   // bar2: staged chunk c+1 visible for next T/QK
    }

    #pragma unroll
    for (int rr = 0; rr < 4; ++rr) {
        const size_t rowoff = ((size_t)(b * SEQ + i0 + wR + lg * 4 + rr)) * DM + h * HD;
        const float inv = 1.0f / l[rr];
        out[rowoff +  0 + lc] = O0[rr] * inv;
        out[rowoff + 16 + lc] = O1[rr] * inv;
        out[rowoff + 32 + lc] = O2[rr] * inv;
        out[rowoff + 48 + lc] = O3[rr] * inv;
    }
}

// ---------------------------------------------------------------------------
extern "C" void kernel_launch(void* const* d_in, const int* in_sizes, int n_in,
                              void* d_out, int out_size, void* d_ws, size_t ws_size,
                              hipStream_t stream) {
    const float* x  = (const float*)d_in[0];
    const float* wq = (const float*)d_in[1];
    const float* bq = (const float*)d_in[2];
    const float* wk = (const float*)d_in[3];
    const float* bk = (const float*)d_in[4];
    const float* wv = (const float*)d_in[5];
    const float* bv = (const float*)d_in[6];
    const float* de = (const float*)d_in[7];
    float* out = (float*)d_out;

    // bf16 workspace layout (~58 MB total, all 16B-aligned)
    const size_t NX = (size_t)BATCH * SEQ * DM;   // 6,291,456
    const size_t NW = (size_t)DM * DM;            //   589,824
    const size_t ND = 2047 * HD;                  //   131,008
    short* xb  = (short*)d_ws;
    short* wqb = xb  + NX;
    short* wkb = wqb + NW;
    short* wvb = wkb + NW;
    short* deb = wvb + NW;
    short* qbw = deb + ND;
    short* kbw = qbw + NX;
    short* vtw = kbw + NX;

    cvt_f32_bf16<<<(int)((NX / 4 + 255) / 256), 256, 0, stream>>>(x,  xb,  (int)(NX / 4));
    cvt_f32_bf16<<<(int)((NW / 4 + 255) / 256), 256, 0, stream>>>(wq, wqb, (int)(NW / 4));
    cvt_f32_bf16<<<(int)((NW / 4 + 255) / 256), 256, 0, stream>>>(wk, wkb, (int)(NW / 4));
    cvt_f32_bf16<<<(int)((NW / 4 + 255) / 256), 256, 0, stream>>>(wv, wvb, (int)(NW / 4));
    cvt_f32_bf16<<<(int)((ND / 4 + 255) / 256), 256, 0, stream>>>(de, deb, (int)(ND / 4));

    qkv_mfma<<<2304, 512, 0, stream>>>(xb, wqb, bq, wkb, bk, wvb, bv,
                                       qbw, kbw, vtw);
    attn_flash<<<768, 512, 0, stream>>>(qbw, kbw, vtw, deb, out);
}